// Round 1
// baseline (647.735 us; speedup 1.0000x reference)
//
#include <hip/hip_runtime.h>
#include <math.h>

#define T_STEPS 32
#define B_SZ    512
#define D_SZ    1024
#define C_SZ    1000

// C[M,N] = scale * (A[M,K] @ B[N,K]^T) + bias[N]
// 64x64 tile, BK=16, 256 threads, 4x4 microtile per thread. M,K multiples of 64/16.
__global__ __launch_bounds__(256) void gemm_bt_f32(
    const float* __restrict__ A, const float* __restrict__ Bm,
    const float* __restrict__ bias, float* __restrict__ C,
    int M, int N, int K, float scale)
{
    __shared__ float As[16][64];
    __shared__ float Bs[16][64];

    const int tid  = threadIdx.x;
    const int tx   = tid & 15;        // n-direction (4 cols each)
    const int ty   = tid >> 4;        // m-direction (4 rows each)
    const int n0   = blockIdx.x * 64;
    const int m0   = blockIdx.y * 64;
    const int lrow = tid >> 2;        // 0..63: tile row to stage
    const int lk   = (tid & 3) * 4;   // 0,4,8,12: k sub-offset (float4)

    float acc[4][4] = {};

    for (int k0 = 0; k0 < K; k0 += 16) {
        // stage A tile (64 rows x 16 k), transposed into As[k][m]
        {
            const float4 av = *(const float4*)(A + (size_t)(m0 + lrow) * K + k0 + lk);
            As[lk + 0][lrow] = av.x;
            As[lk + 1][lrow] = av.y;
            As[lk + 2][lrow] = av.z;
            As[lk + 3][lrow] = av.w;
        }
        // stage B tile (64 rows x 16 k), guarded for N=1000
        {
            const int brow = n0 + lrow;
            float4 bv = make_float4(0.f, 0.f, 0.f, 0.f);
            if (brow < N)
                bv = *(const float4*)(Bm + (size_t)brow * K + k0 + lk);
            Bs[lk + 0][lrow] = bv.x;
            Bs[lk + 1][lrow] = bv.y;
            Bs[lk + 2][lrow] = bv.z;
            Bs[lk + 3][lrow] = bv.w;
        }
        __syncthreads();

        #pragma unroll
        for (int kk = 0; kk < 16; ++kk) {
            const float4 a = *(const float4*)&As[kk][ty * 4];
            const float4 b = *(const float4*)&Bs[kk][tx * 4];
            acc[0][0] += a.x * b.x; acc[0][1] += a.x * b.y; acc[0][2] += a.x * b.z; acc[0][3] += a.x * b.w;
            acc[1][0] += a.y * b.x; acc[1][1] += a.y * b.y; acc[1][2] += a.y * b.z; acc[1][3] += a.y * b.w;
            acc[2][0] += a.z * b.x; acc[2][1] += a.z * b.y; acc[2][2] += a.z * b.z; acc[2][3] += a.z * b.w;
            acc[3][0] += a.w * b.x; acc[3][1] += a.w * b.y; acc[3][2] += a.w * b.z; acc[3][3] += a.w * b.w;
        }
        __syncthreads();
    }

    #pragma unroll
    for (int i = 0; i < 4; ++i) {
        const int r = m0 + ty * 4 + i;
        #pragma unroll
        for (int j = 0; j < 4; ++j) {
            const int c = n0 + tx * 4 + j;
            if (c < N)
                C[(size_t)r * N + c] = scale * acc[i][j] + bias[c];
        }
    }
}

// LIF scan over T for each (b,d); outputs spike count as float.
// v_{t} = 0.5*v_{t-1} + 0.5*h_t ; s = (v >= 1) ; v *= (1-s)
__global__ __launch_bounds__(256) void lif_scan_k(
    const float* __restrict__ h, float* __restrict__ cnt)
{
    const int idx = blockIdx.x * blockDim.x + threadIdx.x;  // over B*D
    const size_t BD = (size_t)B_SZ * D_SZ;
    const float* hp = h + idx;
    float v = 0.f;
    float c = 0.f;
    #pragma unroll
    for (int t = 0; t < T_STEPS; ++t) {
        const float ht = hp[(size_t)t * BD];
        v = 0.5f * (v + ht);
        const float s = (v >= 1.0f) ? 1.0f : 0.0f;
        c += s;
        v *= (1.0f - s);
    }
    cnt[idx] = c;
}

// log_softmax over rows of 1000; one block (256 threads) per row.
__global__ __launch_bounds__(256) void log_softmax_k(
    const float* __restrict__ y, float* __restrict__ out)
{
    __shared__ float red_max[4];
    __shared__ float red_sum[4];

    const int b   = blockIdx.x;
    const int tid = threadIdx.x;
    const float* row = y + (size_t)b * C_SZ;

    float vals[4];
    float m = -1e30f;
    #pragma unroll
    for (int k = 0; k < 4; ++k) {
        const int c = tid + k * 256;
        vals[k] = (c < C_SZ) ? row[c] : -1e30f;
        m = fmaxf(m, vals[k]);
    }
    // wave reduce max (64 lanes)
    #pragma unroll
    for (int off = 32; off > 0; off >>= 1)
        m = fmaxf(m, __shfl_down(m, off, 64));
    const int wave = tid >> 6;
    const int lane = tid & 63;
    if (lane == 0) red_max[wave] = m;
    __syncthreads();
    m = fmaxf(fmaxf(red_max[0], red_max[1]), fmaxf(red_max[2], red_max[3]));

    float s = 0.f;
    #pragma unroll
    for (int k = 0; k < 4; ++k) {
        const int c = tid + k * 256;
        if (c < C_SZ) s += __expf(vals[k] - m);
    }
    #pragma unroll
    for (int off = 32; off > 0; off >>= 1)
        s += __shfl_down(s, off, 64);
    if (lane == 0) red_sum[wave] = s;
    __syncthreads();
    s = red_sum[0] + red_sum[1] + red_sum[2] + red_sum[3];

    const float lse = m + logf(s);
    #pragma unroll
    for (int k = 0; k < 4; ++k) {
        const int c = tid + k * 256;
        if (c < C_SZ) out[(size_t)b * C_SZ + c] = vals[k] - lse;
    }
}

extern "C" void kernel_launch(void* const* d_in, const int* in_sizes, int n_in,
                              void* d_out, int out_size, void* d_ws, size_t ws_size,
                              hipStream_t stream)
{
    const float* x  = (const float*)d_in[0];  // [T,B,D]
    const float* W1 = (const float*)d_in[1];  // [D,D]  (e,d)
    const float* b1 = (const float*)d_in[2];  // [D]
    const float* W2 = (const float*)d_in[3];  // [C,D]  (c,d)
    const float* b2 = (const float*)d_in[4];  // [C]
    float* out = (float*)d_out;               // [B,C]

    float* h   = (float*)d_ws;                           // T*B*D floats (64 MB)
    float* cnt = h + (size_t)T_STEPS * B_SZ * D_SZ;      // B*D floats (2 MB)
    float* y   = cnt + (size_t)B_SZ * D_SZ;              // B*C floats (2 MB)

    // GEMM1: h = x @ W1^T + b1   (M = T*B = 16384, N = D = 1024, K = D = 1024)
    {
        dim3 grid(D_SZ / 64, (T_STEPS * B_SZ) / 64);
        gemm_bt_f32<<<grid, 256, 0, stream>>>(x, W1, b1, h,
                                              T_STEPS * B_SZ, D_SZ, D_SZ, 1.0f);
    }
    // LIF scan -> spike counts per (b,d)
    {
        const int n = B_SZ * D_SZ;
        lif_scan_k<<<n / 256, 256, 0, stream>>>(h, cnt);
    }
    // GEMM2: y = (1/T) * cnt @ W2^T + b2   (M = B = 512, N = C = 1000, K = D = 1024)
    {
        dim3 grid((C_SZ + 63) / 64, B_SZ / 64);
        gemm_bt_f32<<<grid, 256, 0, stream>>>(cnt, W2, b2, y,
                                              B_SZ, C_SZ, D_SZ, 1.0f / (float)T_STEPS);
    }
    // log_softmax rows
    log_softmax_k<<<B_SZ, 256, 0, stream>>>(y, out);
}

// Round 2
// 206.415 us; speedup vs baseline: 3.1380x; 3.1380x over previous
//
#include <hip/hip_runtime.h>
#include <math.h>

#define T_STEPS 32
#define B_SZ    512
#define D_SZ    1024
#define C_SZ    1000

typedef __bf16 bf16x8 __attribute__((ext_vector_type(8)));
typedef float  f32x4  __attribute__((ext_vector_type(4)));

__device__ __forceinline__ unsigned short f2bf(float f) {
    unsigned u = __float_as_uint(f);
    unsigned r = u + 0x7FFFu + ((u >> 16) & 1u);   // RNE
    return (unsigned short)(r >> 16);
}
__device__ __forceinline__ float bf2f(unsigned short b) {
    return __uint_as_float(((unsigned)b) << 16);
}

__device__ __forceinline__ void async_copy16(const void* g, void* l) {
    __builtin_amdgcn_global_load_lds(
        (const __attribute__((address_space(1))) unsigned int*)g,
        (__attribute__((address_space(3))) unsigned int*)l,
        16, 0, 0);
}

// ---------------- fp32 -> bf16 cast (4 elems/thread) ----------------
__global__ __launch_bounds__(256) void cast_f32_bf16(
    const float* __restrict__ s, unsigned short* __restrict__ d, int n4)
{
    const int idx = blockIdx.x * 256 + threadIdx.x;
    if (idx >= n4) return;
    const float4 v = ((const float4*)s)[idx];
    ushort4 o;
    o.x = f2bf(v.x); o.y = f2bf(v.y); o.z = f2bf(v.z); o.w = f2bf(v.w);
    ((ushort4*)d)[idx] = o;
}

// ---------------- bf16 MFMA GEMM: C = scale*(A @ Bm^T) + bias ----------------
// A [M,K] bf16 row-major, Bm [N,K] bf16 row-major, K % 32 == 0, M % 128 == 0.
// 128x128 tile, BK=32, 256 thr = 4 waves (2x2), each wave 64x64 via 4x4
// mfma_f32_16x16x32_bf16 tiles. global_load_lds width=16 staging with XOR
// swizzle on 16B chunks: slot q' = q ^ ((row>>1)&3) -> 2-way-free ds_read_b128.
template<int OUT_BF16>
__global__ __launch_bounds__(256) void gemm_mfma(
    const unsigned short* __restrict__ A, const unsigned short* __restrict__ Bm,
    const float* __restrict__ bias, void* __restrict__ Cout,
    int M, int N, int K, float scale)
{
    __shared__ unsigned short As[128 * 32];
    __shared__ unsigned short Bs[128 * 32];

    const int tid  = threadIdx.x;
    const int wave = tid >> 6;
    const int lane = tid & 63;
    const int lm   = lane & 15;
    const int quad = lane >> 4;
    const int wm   = (wave >> 1) * 64;
    const int wn   = (wave & 1) * 64;
    const int m0   = blockIdx.y * 128;
    const int n0   = blockIdx.x * 128;

    f32x4 acc[4][4];
    #pragma unroll
    for (int i = 0; i < 4; ++i)
        #pragma unroll
        for (int j = 0; j < 4; ++j)
            acc[i][j] = (f32x4){0.f, 0.f, 0.f, 0.f};

    // staging geometry (slot s = p*256 + tid; row = s>>2; phys chunk qs = s&3;
    // global chunk gq = qs ^ ((row>>1)&3))
    int srow[2], sgq[2];
    unsigned ldsoff[2];
    #pragma unroll
    for (int p = 0; p < 2; ++p) {
        const int s = p * 256 + tid;
        srow[p] = s >> 2;
        sgq[p]  = (s & 3) ^ ((srow[p] >> 1) & 3);
        ldsoff[p] = (unsigned)(p * 256 + wave * 64) * 16u;  // wave-uniform
    }
    // fragment-read swizzled chunk index (row bits 1..2 come from lm only)
    const int fq = quad ^ ((lm >> 1) & 3);

    for (int k0 = 0; k0 < K; k0 += 32) {
        #pragma unroll
        for (int p = 0; p < 2; ++p) {
            const int arow = m0 + srow[p];
            async_copy16(A + (size_t)arow * K + k0 + sgq[p] * 8,
                         (char*)As + ldsoff[p]);
            int brow = n0 + srow[p];
            if (brow > N - 1) brow = N - 1;
            async_copy16(Bm + (size_t)brow * K + k0 + sgq[p] * 8,
                         (char*)Bs + ldsoff[p]);
        }
        __syncthreads();

        bf16x8 af[4], bfr[4];
        #pragma unroll
        for (int i = 0; i < 4; ++i) {
            const int ra = wm + i * 16 + lm;
            af[i]  = ((const bf16x8*)As)[ra * 4 + fq];
            const int rb = wn + i * 16 + lm;
            bfr[i] = ((const bf16x8*)Bs)[rb * 4 + fq];
        }
        #pragma unroll
        for (int mi = 0; mi < 4; ++mi)
            #pragma unroll
            for (int ni = 0; ni < 4; ++ni)
                acc[mi][ni] = __builtin_amdgcn_mfma_f32_16x16x32_bf16(
                    af[mi], bfr[ni], acc[mi][ni], 0, 0, 0);
        __syncthreads();
    }

    // epilogue: C[m][n], m = m0+wm+mi*16+quad*4+r, n = n0+wn+ni*16+lm
    #pragma unroll
    for (int ni = 0; ni < 4; ++ni) {
        const int nn = n0 + wn + ni * 16 + lm;
        if (nn >= N) continue;
        const float bv = bias[nn];
        #pragma unroll
        for (int mi = 0; mi < 4; ++mi) {
            const f32x4 v = acc[mi][ni];
            #pragma unroll
            for (int r = 0; r < 4; ++r) {
                const int mm = m0 + wm + mi * 16 + quad * 4 + r;
                const float o = v[r] * scale + bv;
                if (OUT_BF16)
                    ((unsigned short*)Cout)[(size_t)mm * N + nn] = f2bf(o);
                else
                    ((float*)Cout)[(size_t)mm * N + nn] = o;
            }
        }
    }
}

// ---------------- LIF scan over T; spike counts (bf16, exact) ----------------
__global__ __launch_bounds__(256) void lif_scan_k(
    const unsigned short* __restrict__ h, unsigned short* __restrict__ cnt)
{
    const int idx = blockIdx.x * 256 + threadIdx.x;  // over B*D
    const size_t BD = (size_t)B_SZ * D_SZ;
    float v = 0.f, c = 0.f;
    #pragma unroll
    for (int t = 0; t < T_STEPS; ++t) {
        const float ht = bf2f(h[(size_t)t * BD + idx]);
        v = 0.5f * (v + ht);
        const float s = (v >= 1.0f) ? 1.0f : 0.0f;
        c += s;
        v *= (1.0f - s);
    }
    cnt[idx] = f2bf(c);
}

// ---------------- log_softmax over rows of C_SZ ----------------
__global__ __launch_bounds__(256) void log_softmax_k(
    const float* __restrict__ y, float* __restrict__ out)
{
    __shared__ float red_max[4];
    __shared__ float red_sum[4];

    const int b   = blockIdx.x;
    const int tid = threadIdx.x;
    const float* row = y + (size_t)b * C_SZ;

    float vals[4];
    float m = -1e30f;
    #pragma unroll
    for (int k = 0; k < 4; ++k) {
        const int c = tid + k * 256;
        vals[k] = (c < C_SZ) ? row[c] : -1e30f;
        m = fmaxf(m, vals[k]);
    }
    #pragma unroll
    for (int off = 32; off > 0; off >>= 1)
        m = fmaxf(m, __shfl_down(m, off, 64));
    const int wave = tid >> 6;
    const int lane = tid & 63;
    if (lane == 0) red_max[wave] = m;
    __syncthreads();
    m = fmaxf(fmaxf(red_max[0], red_max[1]), fmaxf(red_max[2], red_max[3]));

    float s = 0.f;
    #pragma unroll
    for (int k = 0; k < 4; ++k) {
        const int c = tid + k * 256;
        if (c < C_SZ) s += __expf(vals[k] - m);
    }
    #pragma unroll
    for (int off = 32; off > 0; off >>= 1)
        s += __shfl_down(s, off, 64);
    if (lane == 0) red_sum[wave] = s;
    __syncthreads();
    s = red_sum[0] + red_sum[1] + red_sum[2] + red_sum[3];

    const float lse = m + logf(s);
    #pragma unroll
    for (int k = 0; k < 4; ++k) {
        const int c = tid + k * 256;
        if (c < C_SZ) out[(size_t)b * C_SZ + c] = vals[k] - lse;
    }
}

extern "C" void kernel_launch(void* const* d_in, const int* in_sizes, int n_in,
                              void* d_out, int out_size, void* d_ws, size_t ws_size,
                              hipStream_t stream)
{
    const float* x  = (const float*)d_in[0];  // [T,B,D]
    const float* W1 = (const float*)d_in[1];  // [D,D]
    const float* b1 = (const float*)d_in[2];  // [D]
    const float* W2 = (const float*)d_in[3];  // [C,D]
    const float* b2 = (const float*)d_in[4];  // [C]
    float* out = (float*)d_out;               // [B,C]

    char* ws = (char*)d_ws;
    // layout (within the 71,303,168 B budget proven by round 1):
    unsigned short* x_bf   = (unsigned short*)(ws);              // 33,554,432 B
    unsigned short* W1_bf  = (unsigned short*)(ws + 33554432);   //  2,097,152 B
    unsigned short* h_bf   = (unsigned short*)(ws + 35651584);   // 33,554,432 B
    unsigned short* cnt_bf = (unsigned short*)(ws + 69206016);   //  1,048,576 B
    // overlapped (regions dead by the time these are written):
    float*          y      = (float*)(ws);                       // over x_bf
    unsigned short* W2_bf  = (unsigned short*)(ws + 33554432);   // over W1_bf

    const int MBD = T_STEPS * B_SZ;           // 16384

    // 1) casts for GEMM1
    cast_f32_bf16<<<(MBD * D_SZ / 4) / 256, 256, 0, stream>>>(x, x_bf, MBD * D_SZ / 4);
    cast_f32_bf16<<<(D_SZ * D_SZ / 4) / 256, 256, 0, stream>>>(W1, W1_bf, D_SZ * D_SZ / 4);

    // 2) GEMM1: h = x @ W1^T + b1  (M=16384, N=1024, K=1024), bf16 out
    {
        dim3 grid(D_SZ / 128, MBD / 128);
        gemm_mfma<1><<<grid, 256, 0, stream>>>(x_bf, W1_bf, b1, h_bf,
                                               MBD, D_SZ, D_SZ, 1.0f);
    }
    // 3) LIF scan -> bf16 spike counts (exact integers)
    lif_scan_k<<<(B_SZ * D_SZ) / 256, 256, 0, stream>>>(h_bf, cnt_bf);

    // 4) cast W2 (into W1_bf slot, dead after GEMM1)
    cast_f32_bf16<<<(C_SZ * D_SZ / 4) / 256, 256, 0, stream>>>(W2, W2_bf, C_SZ * D_SZ / 4);

    // 5) GEMM2: y = (1/T) * cnt @ W2^T + b2  (M=512, N=1000, K=1024), fp32 out
    {
        dim3 grid((C_SZ + 127) / 128, B_SZ / 128);
        gemm_mfma<0><<<grid, 256, 0, stream>>>(cnt_bf, W2_bf, b2, y,
                                               B_SZ, C_SZ, D_SZ, 1.0f / (float)T_STEPS);
    }
    // 6) log_softmax
    log_softmax_k<<<B_SZ, 256, 0, stream>>>(y, out);
}

// Round 3
// 171.053 us; speedup vs baseline: 3.7868x; 1.2067x over previous
//
#include <hip/hip_runtime.h>
#include <math.h>

#define T_STEPS 32
#define B_SZ    512
#define D_SZ    1024
#define C_SZ    1000
#define KZ      8           // GEMM2 split-K factor
#define HP      132         // LDS h-tile pitch (bf16) — breaks quad bank aliasing

typedef __bf16 bf16x8 __attribute__((ext_vector_type(8)));
typedef float  f32x4  __attribute__((ext_vector_type(4)));

__device__ __forceinline__ unsigned short f2bf(float f) {
    unsigned u = __float_as_uint(f);
    unsigned r = u + 0x7FFFu + ((u >> 16) & 1u);   // RNE
    return (unsigned short)(r >> 16);
}
__device__ __forceinline__ float bf2f(unsigned short b) {
    return __uint_as_float(((unsigned)b) << 16);
}

__device__ __forceinline__ void async_copy16(const void* g, void* l) {
    __builtin_amdgcn_global_load_lds(
        (const __attribute__((address_space(1))) unsigned int*)g,
        (__attribute__((address_space(3))) unsigned int*)l,
        16, 0, 0);
}

// ---------------- fp32 -> bf16 casts ----------------
__global__ __launch_bounds__(256) void cast_x_k(
    const float* __restrict__ s, unsigned short* __restrict__ d)
{
    const int idx = blockIdx.x * 256 + threadIdx.x;
    const float4 v = ((const float4*)s)[idx];
    ushort4 o;
    o.x = f2bf(v.x); o.y = f2bf(v.y); o.z = f2bf(v.z); o.w = f2bf(v.w);
    ((ushort4*)d)[idx] = o;
}

// W1 (1024*1024) and W2 (1000*1024) in one launch.
__global__ __launch_bounds__(256) void cast_w_k(
    const float* __restrict__ W1, unsigned short* __restrict__ W1o,
    const float* __restrict__ W2, unsigned short* __restrict__ W2o)
{
    const int idx = blockIdx.x * 256 + threadIdx.x;
    const int n1 = (D_SZ * D_SZ) / 4;          // 262144
    const float4 v = (idx < n1) ? ((const float4*)W1)[idx]
                                : ((const float4*)W2)[idx - n1];
    ushort4 o;
    o.x = f2bf(v.x); o.y = f2bf(v.y); o.z = f2bf(v.z); o.w = f2bf(v.w);
    if (idx < n1) ((ushort4*)W1o)[idx] = o;
    else          ((ushort4*)W2o)[idx - n1] = o;
}

// ---------------- fused GEMM1 + bias + LIF scan -> spike counts ----------------
// A = x_bf [T*B, D] row-major; Bm = W1_bf [D, D]; cnt [B, D] bf16.
// Block tile: M-rows = {t*512 + b0 + bb : t in [0,32), bb in [0,4)} (local row
// rho = t*4+bb), N-tile 128 wide. 256 thr = 4 waves (2x2), 16x16x32 bf16 MFMA.
// After K-loop: h-tile -> LDS (pitch HP), per-column LIF scan over t, write counts.
__global__ __launch_bounds__(256) void gemm1_scan_k(
    const unsigned short* __restrict__ A, const unsigned short* __restrict__ Bm,
    const float* __restrict__ bias, unsigned short* __restrict__ cnt)
{
    __shared__ __align__(16) unsigned short smem[128 * HP];  // 33792 B
    unsigned short* As = smem;           // 8 KB staging (aliased by h-tile later)
    unsigned short* Bs = smem + 4096;    // 8 KB

    const int tid  = threadIdx.x;
    const int wave = tid >> 6;
    const int lane = tid & 63;
    const int lm   = lane & 15;
    const int quad = lane >> 4;
    const int wm   = (wave >> 1) * 64;
    const int wn   = (wave & 1) * 64;

    // XCD swizzle: blocks sharing the A-tile (same y) land on the same XCD
    const int f  = blockIdx.x;
    const int yb = f & 127;          // 128 b-tiles
    const int xb = f >> 7;           // 8 n-tiles
    const int b0 = yb * 4;
    const int n0 = xb * 128;

    f32x4 acc[4][4];
    #pragma unroll
    for (int i = 0; i < 4; ++i)
        #pragma unroll
        for (int j = 0; j < 4; ++j)
            acc[i][j] = (f32x4){0.f, 0.f, 0.f, 0.f};

    int srowA[2], sgq[2];
    size_t arowoff[2];
    unsigned ldsoff[2];
    #pragma unroll
    for (int p = 0; p < 2; ++p) {
        const int s = p * 256 + tid;
        const int rho = s >> 2;                       // tile-local row
        srowA[p] = rho;
        sgq[p]  = (s & 3) ^ ((rho >> 1) & 3);
        arowoff[p] = (size_t)((rho >> 2) * 512 + b0 + (rho & 3)) * D_SZ; // t*512+b
        ldsoff[p] = (unsigned)(p * 256 + wave * 64) * 16u;
    }
    const int fq = quad ^ ((lm >> 1) & 3);

    for (int k0 = 0; k0 < D_SZ; k0 += 32) {
        #pragma unroll
        for (int p = 0; p < 2; ++p) {
            async_copy16(A + arowoff[p] + k0 + sgq[p] * 8, (char*)As + ldsoff[p]);
            async_copy16(Bm + (size_t)(n0 + srowA[p]) * D_SZ + k0 + sgq[p] * 8,
                         (char*)Bs + ldsoff[p]);
        }
        __syncthreads();

        bf16x8 af[4], bfr[4];
        #pragma unroll
        for (int i = 0; i < 4; ++i) {
            af[i]  = ((const bf16x8*)As)[(wm + i * 16 + lm) * 4 + fq];
            bfr[i] = ((const bf16x8*)Bs)[(wn + i * 16 + lm) * 4 + fq];
        }
        #pragma unroll
        for (int mi = 0; mi < 4; ++mi)
            #pragma unroll
            for (int ni = 0; ni < 4; ++ni)
                acc[mi][ni] = __builtin_amdgcn_mfma_f32_16x16x32_bf16(
                    af[mi], bfr[ni], acc[mi][ni], 0, 0, 0);
        __syncthreads();
    }

    // h-tile (+bias) -> LDS. local row rho = wm+mi*16+quad*4+r, col = wn+ni*16+lm
    #pragma unroll
    for (int ni = 0; ni < 4; ++ni) {
        const int nn = wn + ni * 16 + lm;
        const float bv = bias[n0 + nn];
        #pragma unroll
        for (int mi = 0; mi < 4; ++mi) {
            const f32x4 v = acc[mi][ni];
            #pragma unroll
            for (int r = 0; r < 4; ++r)
                smem[(wm + mi * 16 + quad * 4 + r) * HP + nn] = f2bf(v[r] + bv);
        }
    }
    __syncthreads();

    // LIF scan: column (bb, c): h[t] at local row t*4+bb. 512 cols, 2/thread.
    #pragma unroll
    for (int rep = 0; rep < 2; ++rep) {
        const int flat = rep * 256 + tid;
        const int bb = flat >> 7;
        const int c  = flat & 127;
        float v = 0.f, cv = 0.f;
        #pragma unroll
        for (int t = 0; t < T_STEPS; ++t) {
            const float ht = bf2f(smem[(t * 4 + bb) * HP + c]);
            v = 0.5f * (v + ht);
            const float s = (v >= 1.0f) ? 1.0f : 0.0f;
            cv += s;
            v *= (1.0f - s);
        }
        cnt[(size_t)(b0 + bb) * D_SZ + n0 + c] = f2bf(cv);
    }
}

// ---------------- GEMM2 split-K: partial[z][m][n] = cnt @ W2^T (K-slice) ----------------
__global__ __launch_bounds__(256) void gemm2_splitk_k(
    const unsigned short* __restrict__ A, const unsigned short* __restrict__ Bm,
    float* __restrict__ partial)
{
    __shared__ __align__(16) unsigned short As[128 * 32];
    __shared__ __align__(16) unsigned short Bs[128 * 32];

    const int tid  = threadIdx.x;
    const int wave = tid >> 6;
    const int lane = tid & 63;
    const int lm   = lane & 15;
    const int quad = lane >> 4;
    const int wm   = (wave >> 1) * 64;
    const int wn   = (wave & 1) * 64;
    const int n0   = blockIdx.x * 128;
    const int m0   = blockIdx.y * 128;
    const int kz   = blockIdx.z;

    f32x4 acc[4][4];
    #pragma unroll
    for (int i = 0; i < 4; ++i)
        #pragma unroll
        for (int j = 0; j < 4; ++j)
            acc[i][j] = (f32x4){0.f, 0.f, 0.f, 0.f};

    int srow[2], sgq[2];
    unsigned ldsoff[2];
    #pragma unroll
    for (int p = 0; p < 2; ++p) {
        const int s = p * 256 + tid;
        srow[p] = s >> 2;
        sgq[p]  = (s & 3) ^ ((srow[p] >> 1) & 3);
        ldsoff[p] = (unsigned)(p * 256 + wave * 64) * 16u;
    }
    const int fq = quad ^ ((lm >> 1) & 3);

    const int kbeg = kz * (D_SZ / KZ);
    for (int k0 = kbeg; k0 < kbeg + D_SZ / KZ; k0 += 32) {
        #pragma unroll
        for (int p = 0; p < 2; ++p) {
            async_copy16(A + (size_t)(m0 + srow[p]) * D_SZ + k0 + sgq[p] * 8,
                         (char*)As + ldsoff[p]);
            int brow = n0 + srow[p];
            if (brow > C_SZ - 1) brow = C_SZ - 1;
            async_copy16(Bm + (size_t)brow * D_SZ + k0 + sgq[p] * 8,
                         (char*)Bs + ldsoff[p]);
        }
        __syncthreads();

        bf16x8 af[4], bfr[4];
        #pragma unroll
        for (int i = 0; i < 4; ++i) {
            af[i]  = ((const bf16x8*)As)[(wm + i * 16 + lm) * 4 + fq];
            bfr[i] = ((const bf16x8*)Bs)[(wn + i * 16 + lm) * 4 + fq];
        }
        #pragma unroll
        for (int mi = 0; mi < 4; ++mi)
            #pragma unroll
            for (int ni = 0; ni < 4; ++ni)
                acc[mi][ni] = __builtin_amdgcn_mfma_f32_16x16x32_bf16(
                    af[mi], bfr[ni], acc[mi][ni], 0, 0, 0);
        __syncthreads();
    }

    #pragma unroll
    for (int ni = 0; ni < 4; ++ni) {
        const int nn = n0 + wn + ni * 16 + lm;
        if (nn >= C_SZ) continue;
        #pragma unroll
        for (int mi = 0; mi < 4; ++mi) {
            const f32x4 v = acc[mi][ni];
            #pragma unroll
            for (int r = 0; r < 4; ++r) {
                const int mm = m0 + wm + mi * 16 + quad * 4 + r;
                partial[((size_t)kz * B_SZ + mm) * C_SZ + nn] = v[r];
            }
        }
    }
}

// ---------------- reduce partials + bias + log_softmax ----------------
__global__ __launch_bounds__(256) void reduce_lsm_k(
    const float* __restrict__ partial, const float* __restrict__ b2,
    float* __restrict__ out)
{
    __shared__ float red_max[4];
    __shared__ float red_sum[4];

    const int b   = blockIdx.x;
    const int tid = threadIdx.x;

    float vals[4];
    float m = -1e30f;
    #pragma unroll
    for (int k = 0; k < 4; ++k) {
        const int c = tid + k * 256;
        if (c < C_SZ) {
            float s = 0.f;
            #pragma unroll
            for (int z = 0; z < KZ; ++z)
                s += partial[((size_t)z * B_SZ + b) * C_SZ + c];
            vals[k] = s * (1.0f / (float)T_STEPS) + b2[c];
        } else {
            vals[k] = -1e30f;
        }
        m = fmaxf(m, vals[k]);
    }
    #pragma unroll
    for (int off = 32; off > 0; off >>= 1)
        m = fmaxf(m, __shfl_down(m, off, 64));
    const int wave = tid >> 6;
    const int lane = tid & 63;
    if (lane == 0) red_max[wave] = m;
    __syncthreads();
    m = fmaxf(fmaxf(red_max[0], red_max[1]), fmaxf(red_max[2], red_max[3]));

    float s = 0.f;
    #pragma unroll
    for (int k = 0; k < 4; ++k) {
        const int c = tid + k * 256;
        if (c < C_SZ) s += __expf(vals[k] - m);
    }
    #pragma unroll
    for (int off = 32; off > 0; off >>= 1)
        s += __shfl_down(s, off, 64);
    if (lane == 0) red_sum[wave] = s;
    __syncthreads();
    s = red_sum[0] + red_sum[1] + red_sum[2] + red_sum[3];

    const float lse = m + logf(s);
    #pragma unroll
    for (int k = 0; k < 4; ++k) {
        const int c = tid + k * 256;
        if (c < C_SZ) out[(size_t)b * C_SZ + c] = vals[k] - lse;
    }
}

extern "C" void kernel_launch(void* const* d_in, const int* in_sizes, int n_in,
                              void* d_out, int out_size, void* d_ws, size_t ws_size,
                              hipStream_t stream)
{
    const float* x  = (const float*)d_in[0];  // [T,B,D]
    const float* W1 = (const float*)d_in[1];  // [D,D]
    const float* b1 = (const float*)d_in[2];  // [D]
    const float* W2 = (const float*)d_in[3];  // [C,D]
    const float* b2 = (const float*)d_in[4];  // [C]
    float* out = (float*)d_out;               // [B,C]

    char* ws = (char*)d_ws;
    unsigned short* x_bf    = (unsigned short*)(ws);              // 33,554,432 B
    unsigned short* W1_bf   = (unsigned short*)(ws + 33554432);   //  2,097,152 B
    unsigned short* W2_bf   = (unsigned short*)(ws + 35651584);   //  2,048,000 B
    unsigned short* cnt_bf  = (unsigned short*)(ws + 37699584);   //  1,048,576 B
    float*          partial = (float*)(ws + 38748160);            // 16,384,000 B
    // total 55,132,160 B < ws_size (71,303,168 B proven round 1)

    const int MBD = T_STEPS * B_SZ;           // 16384

    // 1) casts
    cast_x_k<<<(MBD * D_SZ / 4) / 256, 256, 0, stream>>>(x, x_bf);
    cast_w_k<<<((D_SZ * D_SZ + C_SZ * D_SZ) / 4) / 256, 256, 0, stream>>>(
        W1, W1_bf, W2, W2_bf);

    // 2) fused GEMM1 + bias + LIF scan -> counts (1024 blocks, XCD-swizzled)
    gemm1_scan_k<<<(B_SZ / 4) * (D_SZ / 128), 256, 0, stream>>>(
        x_bf, W1_bf, b1, cnt_bf);

    // 3) GEMM2 split-K partials
    {
        dim3 grid((C_SZ + 127) / 128, B_SZ / 128, KZ);
        gemm2_splitk_k<<<grid, 256, 0, stream>>>(cnt_bf, W2_bf, partial);
    }

    // 4) reduce + bias + log_softmax
    reduce_lsm_k<<<B_SZ, 256, 0, stream>>>(partial, b2, out);
}